// Round 11
// baseline (125.171 us; speedup 1.0000x reference)
//
#include <hip/hip_runtime.h>
#include <float.h>

#define Bb 2
#define Ll 256
#define Ss 384
#define Hh 768
#define Tc 16
#define Dc 50
#define WD 100
#define CV 128
#define NG 200     // 4*Dc gates
#define OUTC 968   // H + WD + 2*Dc

// ws layout (floats):
//   [0, 128)      minv partials
//   [128, ...)    xproj table [2][128][200], bias folded in

__device__ inline float tanh_fast(float x) {
    float e = __expf(2.f * x);
    return 1.f - 2.f / (e + 1.f);
}
__device__ inline float sigmoid_fast(float x) {
    return 1.f / (1.f + __expf(-x));
}

// ================= kernel 1: min partials | xproj =================
// grid 144: [0,128) min, [128,144) xproj

__global__ __launch_bounds__(256) void kernel1(
        const float* __restrict__ bert, const float* __restrict__ char_table,
        const float* __restrict__ Wih_f, const float* __restrict__ bih_f, const float* __restrict__ bhh_f,
        const float* __restrict__ Wih_b, const float* __restrict__ bih_b, const float* __restrict__ bhh_b,
        float* __restrict__ minp, float* __restrict__ xpt) {
    int blk = blockIdx.x, tid = threadIdx.x;
    if (blk < 128) {
        const int n4 = (Bb * Ss * Hh) / 4;       // 147456 float4
        const float4* b4 = (const float4*)bert;
        float m = FLT_MAX;
        for (int i = blk * 256 + tid; i < n4; i += 128 * 256) {
            float4 v = b4[i];
            m = fminf(m, fminf(fminf(v.x, v.y), fminf(v.z, v.w)));
        }
        #pragma unroll
        for (int off = 32; off; off >>= 1) m = fminf(m, __shfl_down(m, off, 64));
        __shared__ float red[4];
        if ((tid & 63) == 0) red[tid >> 6] = m;
        __syncthreads();
        if (tid == 0) minp[blk] = fminf(fminf(red[0], red[1]), fminf(red[2], red[3]));
    } else {
        int idx = blk - 128;            // dir*8 + cid-chunk
        int dir = idx >> 3, c0 = (idx & 7) * 16;
        const float* Wih = dir ? Wih_b : Wih_f;
        const float* bih = dir ? bih_b : bih_f;
        const float* bhh = dir ? bhh_b : bhh_f;
        __shared__ float ct[16][Dc];
        for (int e = tid; e < 16 * Dc; e += 256)
            ((float*)ct)[e] = char_table[c0 * Dc + e];
        __syncthreads();
        if (tid < NG) {
            float w[Dc];
            #pragma unroll
            for (int j = 0; j < Dc; j++) w[j] = Wih[tid * Dc + j];
            float bias = bih[tid] + bhh[tid];
            for (int cid = 0; cid < 16; cid++) {
                float a = bias;
                #pragma unroll
                for (int j = 0; j < Dc; j++) a += w[j] * ct[cid][j];
                xpt[(dir * CV + c0 + cid) * NG + tid] = a;
            }
        }
    }
}

// ================= kernel2: fused lstm | word | embed =================
// grid 1472, roles INTERLEAVED (R9: fused interleave beat the serial split):
//   blk < 1152 : blk%3==0 -> word id blk/3 (0..383),
//                else     -> lstm id (blk/3)*2 + blk%3 - 1 (0..767)
//   blk < 1408 : lstm id 768 + (blk-1152)
//   else       : embed id blk-1408
// lstm: R8/R10 readlane form (unchanged).
// word: 4 rows x float4-h (256 h per wave, 3 hc chunks). The 8-row float2
//       form issued 192 ds_read_b128/wave on the single per-CU LDS pipe
//       (~12cyc each) -- the measured word-section bottleneck. This form
//       halves LDS reads (1 b128 mask read per k, 4 rows) at the same
//       VALU total; bert L2 traffic doubles (cheap, L2-resident).

__global__ __launch_bounds__(256, 4) void kernel2(
        const int* __restrict__ char_ids, const int* __restrict__ char_count,
        const float* __restrict__ Whh_f, const float* __restrict__ Whh_b,
        const float* __restrict__ xpt,
        const float* __restrict__ bert, const int* __restrict__ p2w,
        const float* __restrict__ minp,
        const int* __restrict__ word_ids, const float* __restrict__ word_table,
        float* __restrict__ out) {
    __shared__ __align__(16) char smem[22544];
    int blk = blockIdx.x, tid = threadIdx.x;

    int role, id;
    if (blk < 1152) {
        int g = blk / 3, r3 = blk - g * 3;
        role = r3 == 0 ? 0 : 1;
        id = r3 == 0 ? g : g * 2 + (r3 - 1);
    } else if (blk < 1408) { role = 1; id = 768 + (blk - 1152); }
    else { role = 2; id = blk - 1408; }

    if (role == 1) {
        // ---------------- char bi-LSTM (readlane broadcast) ----------------
        float (*xg)[NG] = (float (*)[NG])smem;            // 12800
        float (*gsb)[NG] = (float (*)[NG])(smem + 12800); // 1600
        int*   scid = (int*)(smem + 14400);               // 64

        int n = id >> 1, dir = id & 1;
        const float* Whh = dir ? Whh_b : Whh_f;
        int lane = tid & 63;

        int len = char_count[n];
        if (len < 1) len = 1;
        if (tid < Tc) {
            int st = dir ? (tid < len ? len - 1 - tid : tid) : tid;  // bwd: reverse valid prefix
            scid[tid] = char_ids[n * Tc + st];
        }
        __syncthreads();

        // stage xproj rows as float4 (row stride 200 floats = 800B, 16B aligned)
        for (int e = tid; e < Tc * (NG / 4); e += 256) {
            int t = e / 50, q = e - t * 50;
            ((float4*)xg[t])[q] = ((const float4*)&xpt[(dir * CV + scid[t]) * NG])[q];
        }
        // recurrent weight row -> regs, defined for ALL lanes (clamped row),
        // constant indices only (fully unrolled) => register-resident
        int wrow = tid < NG ? tid : NG - 1;
        bool istanh = (tid >= 100 && tid < 150);          // cell-gate rows
        float w[50];
        #pragma unroll
        for (int j = 0; j < 50; j++) w[j] = Whh[wrow * 50 + j];
        __syncthreads();

        int ch = lane < 50 ? lane : 49;                   // state channel this lane tracks
        float c = 0.f, h = 0.f, maxv = -FLT_MAX;
        for (int t = 0; t < Tc; t++) {
            // ---- A: gate pre-activation, h broadcast from own wave's lanes ----
            int hb = __float_as_int(h);
            float g0 = xg[t][wrow], g1 = 0.f, g2 = 0.f, g3 = 0.f;
            #pragma unroll
            for (int j = 0; j < 48; j += 4) {
                g0 = fmaf(__int_as_float(__builtin_amdgcn_readlane(hb, j)),     w[j],     g0);
                g1 = fmaf(__int_as_float(__builtin_amdgcn_readlane(hb, j + 1)), w[j + 1], g1);
                g2 = fmaf(__int_as_float(__builtin_amdgcn_readlane(hb, j + 2)), w[j + 2], g2);
                g3 = fmaf(__int_as_float(__builtin_amdgcn_readlane(hb, j + 3)), w[j + 3], g3);
            }
            g0 = fmaf(__int_as_float(__builtin_amdgcn_readlane(hb, 48)), w[48], g0);
            g1 = fmaf(__int_as_float(__builtin_amdgcn_readlane(hb, 49)), w[49], g1);
            float g = (g0 + g1) + (g2 + g3);
            if (tid < NG)
                gsb[t & 1][tid] = istanh ? tanh_fast(g) : sigmoid_fast(g);
            __syncthreads();                               // only barrier per step
            // ---- B: state update, redundant in every wave (h stays lane-local).
            float si = gsb[t & 1][ch];
            float sf = gsb[t & 1][ch + 50];
            float tg = gsb[t & 1][ch + 100];
            float so = gsb[t & 1][ch + 150];
            c = sf * c + si * tg;
            h = so * tanh_fast(c);
            if (t < len) maxv = fmaxf(maxv, h);            // ragged max
        }
        if (tid < 50)
            out[(size_t)n * OUTC + (Hh + WD) + dir * Dc + tid] = maxv;
    } else if (role == 0) {
        // ------- word_reps masked max, branchless, 4 rows x float4-h -------
        float (*sm)[4] = (float (*)[4])smem;                        // 6144
        float (*sacc)[4][256] = (float (*)[4][256])(smem + 6144);   // 16384
        float* sminv = (float*)(smem + 22528);

        int hc  = id % 3;              // h-chunk of 256
        int lt  = (id / 3) & 63;       // l-tile of 4
        int b   = id / 192;
        int l0  = lt * 4;

        // stage mask bias, coalesced global reads (s-fast within a row)
        const int* pm = p2w + ((size_t)(b * Ll + l0)) * Ss;
        for (int e = tid; e < 4 * Ss; e += 256) {
            int r = e / Ss, s = e - r * Ss;
            sm[s][r] = pm[r * Ss + s] ? 0.f : -FLT_MAX;
        }
        if (tid < 64) {
            float m = fminf(minp[tid], minp[tid + 64]);
            #pragma unroll
            for (int off = 32; off; off >>= 1) m = fminf(m, __shfl_down(m, off, 64));
            if (tid == 0) *sminv = m;
        }
        __syncthreads();

        int w    = tid >> 6;           // wave -> s range [w*96, w*96+96)
        int lane = tid & 63;
        int s0 = w * 96;

        // bert row s = 192 float4; lane covers h = hc*256 + lane*4 .. +3
        const float4* bb4 = (const float4*)(bert + (size_t)b * Ss * Hh) + hc * 64 + lane;
        float4 acc[4];
        #pragma unroll
        for (int r = 0; r < 4; r++) acc[r] = make_float4(-FLT_MAX, -FLT_MAX, -FLT_MAX, -FLT_MAX);

        for (int jo = 0; jo < 96; jo += 8) {       // 8 loads in flight per group
            float4 v[8];
            #pragma unroll
            for (int k = 0; k < 8; k++) v[k] = bb4[(size_t)(s0 + jo + k) * 192];
            #pragma unroll
            for (int k = 0; k < 8; k++) {
                int j = s0 + jo + k;
                float4 q = *(const float4*)&sm[j][0];   // ONE b128 broadcast: rows 0..3
                acc[0].x = fmaxf(acc[0].x, v[k].x + q.x);
                acc[0].y = fmaxf(acc[0].y, v[k].y + q.x);
                acc[0].z = fmaxf(acc[0].z, v[k].z + q.x);
                acc[0].w = fmaxf(acc[0].w, v[k].w + q.x);
                acc[1].x = fmaxf(acc[1].x, v[k].x + q.y);
                acc[1].y = fmaxf(acc[1].y, v[k].y + q.y);
                acc[1].z = fmaxf(acc[1].z, v[k].z + q.y);
                acc[1].w = fmaxf(acc[1].w, v[k].w + q.y);
                acc[2].x = fmaxf(acc[2].x, v[k].x + q.z);
                acc[2].y = fmaxf(acc[2].y, v[k].y + q.z);
                acc[2].z = fmaxf(acc[2].z, v[k].z + q.z);
                acc[2].w = fmaxf(acc[2].w, v[k].w + q.z);
                acc[3].x = fmaxf(acc[3].x, v[k].x + q.w);
                acc[3].y = fmaxf(acc[3].y, v[k].y + q.w);
                acc[3].z = fmaxf(acc[3].z, v[k].z + q.w);
                acc[3].w = fmaxf(acc[3].w, v[k].w + q.w);
            }
        }
        #pragma unroll
        for (int r = 0; r < 4; r++)
            *(float4*)&sacc[w][r][lane * 4] = acc[r];
        __syncthreads();

        float mv = *sminv;
        for (int e = tid; e < 4 * 256; e += 256) {
            int r = e >> 8, cx = e & 255;
            float m = fmaxf(fmaxf(sacc[0][r][cx], sacc[1][r][cx]),
                            fmaxf(sacc[2][r][cx], sacc[3][r][cx]));
            if (m == -FLT_MAX) m = mv;             // fully-masked row -> global min fill
            out[((size_t)(b * Ll + l0 + r)) * OUTC + hc * 256 + cx] = m;
        }
    } else {
        // ---------------- word embedding gather ----------------
        for (int i = id * 256 + tid; i < Bb * Ll * WD; i += 64 * 256) {
            int bl = i / WD, d = i - bl * WD;
            out[(size_t)bl * OUTC + Hh + d] = word_table[(size_t)word_ids[bl] * WD + d];
        }
    }
}

extern "C" void kernel_launch(void* const* d_in, const int* in_sizes, int n_in,
                              void* d_out, int out_size, void* d_ws, size_t ws_size,
                              hipStream_t stream) {
    const float* bert       = (const float*)d_in[0];
    const int*   p2w        = (const int*)d_in[1];
    const int*   word_ids   = (const int*)d_in[2];
    const int*   char_count = (const int*)d_in[3];
    const int*   char_ids   = (const int*)d_in[4];
    // d_in[5] token_masks_char: consistent with char_count, unused
    const float* word_table = (const float*)d_in[6];
    const float* char_table = (const float*)d_in[7];
    const float* Wih_f = (const float*)d_in[8];
    const float* Whh_f = (const float*)d_in[9];
    const float* bih_f = (const float*)d_in[10];
    const float* bhh_f = (const float*)d_in[11];
    const float* Wih_b = (const float*)d_in[12];
    const float* Whh_b = (const float*)d_in[13];
    const float* bih_b = (const float*)d_in[14];
    const float* bhh_b = (const float*)d_in[15];
    float* out = (float*)d_out;

    float* minp = (float*)d_ws;          // 128 floats
    float* xpt  = minp + 128;            // 2*128*200 floats

    kernel1<<<144, 256, 0, stream>>>(
        bert, char_table, Wih_f, bih_f, bhh_f, Wih_b, bih_b, bhh_b,
        minp, xpt);
    kernel2<<<1472, 256, 0, stream>>>(
        char_ids, char_count, Whh_f, Whh_b, xpt, bert, p2w, minp,
        word_ids, word_table, out);
}

// Round 12
// 123.609 us; speedup vs baseline: 1.0126x; 1.0126x over previous
//
#include <hip/hip_runtime.h>
#include <float.h>

#define Bb 2
#define Ll 256
#define Ss 384
#define Hh 768
#define Tc 16
#define Dc 50
#define WD 100
#define CV 128
#define NG 200     // 4*Dc gates
#define OUTC 968   // H + WD + 2*Dc

// ws layout (floats):
//   [0, 128)      minv partials
//   [128, ...)    xproj table [2][128][200], bias folded in

__device__ inline float tanh_fast(float x) {
    float e = __expf(2.f * x);
    return 1.f - 2.f / (e + 1.f);
}
__device__ inline float sigmoid_fast(float x) {
    return 1.f / (1.f + __expf(-x));
}

// ================= kernel 1: min partials | xproj =================
// grid 144: [0,128) min, [128,144) xproj

__global__ __launch_bounds__(256) void kernel1(
        const float* __restrict__ bert, const float* __restrict__ char_table,
        const float* __restrict__ Wih_f, const float* __restrict__ bih_f, const float* __restrict__ bhh_f,
        const float* __restrict__ Wih_b, const float* __restrict__ bih_b, const float* __restrict__ bhh_b,
        float* __restrict__ minp, float* __restrict__ xpt) {
    int blk = blockIdx.x, tid = threadIdx.x;
    if (blk < 128) {
        const int n4 = (Bb * Ss * Hh) / 4;       // 147456 float4
        const float4* b4 = (const float4*)bert;
        float m = FLT_MAX;
        for (int i = blk * 256 + tid; i < n4; i += 128 * 256) {
            float4 v = b4[i];
            m = fminf(m, fminf(fminf(v.x, v.y), fminf(v.z, v.w)));
        }
        #pragma unroll
        for (int off = 32; off; off >>= 1) m = fminf(m, __shfl_down(m, off, 64));
        __shared__ float red[4];
        if ((tid & 63) == 0) red[tid >> 6] = m;
        __syncthreads();
        if (tid == 0) minp[blk] = fminf(fminf(red[0], red[1]), fminf(red[2], red[3]));
    } else {
        int idx = blk - 128;            // dir*8 + cid-chunk
        int dir = idx >> 3, c0 = (idx & 7) * 16;
        const float* Wih = dir ? Wih_b : Wih_f;
        const float* bih = dir ? bih_b : bih_f;
        const float* bhh = dir ? bhh_b : bhh_f;
        __shared__ float ct[16][Dc];
        for (int e = tid; e < 16 * Dc; e += 256)
            ((float*)ct)[e] = char_table[c0 * Dc + e];
        __syncthreads();
        if (tid < NG) {
            float w[Dc];
            #pragma unroll
            for (int j = 0; j < Dc; j++) w[j] = Wih[tid * Dc + j];
            float bias = bih[tid] + bhh[tid];
            for (int cid = 0; cid < 16; cid++) {
                float a = bias;
                #pragma unroll
                for (int j = 0; j < Dc; j++) a += w[j] * ct[cid][j];
                xpt[(dir * CV + c0 + cid) * NG + tid] = a;
            }
        }
    }
}

// ================= kernel2: fused lstm | word | embed =================
// grid 1472, roles INTERLEAVED (R9: fused interleave beat the serial split):
//   blk < 1152 : blk%3==0 -> word id blk/3 (0..383),
//                else     -> lstm id (blk/3)*2 + blk%3 - 1 (0..767)
//   blk < 1408 : lstm id 768 + (blk-1152)
//   else       : embed id blk-1408
//
// lstm: recurrent weights as 25 INDIVIDUALLY-NAMED float2 locals (w0..w24).
//       Every prior variant (array w[50/52], with or without asm pins)
//       compiled to VGPR_Count 32-40 < the 50-float weight set: the
//       allocator REMATERIALIZED all weight loads inside the t-loop
//       (~50 VMEM issues/wave/step = ~20 us invariant across 4 rounds of
//       structural nulls). Named scalars are plain SSA values the
//       allocator keeps resident; float2 halves the load count and is
//       8B-aligned (wrow*200 % 8 == 0). SUCCESS CRITERION: VGPR >= 72.
// word: R11 form -- 4 rows x float4-h, branchless additive-bias masked max.

__global__ __launch_bounds__(256, 4) void kernel2(
        const int* __restrict__ char_ids, const int* __restrict__ char_count,
        const float* __restrict__ Whh_f, const float* __restrict__ Whh_b,
        const float* __restrict__ xpt,
        const float* __restrict__ bert, const int* __restrict__ p2w,
        const float* __restrict__ minp,
        const int* __restrict__ word_ids, const float* __restrict__ word_table,
        float* __restrict__ out) {
    __shared__ __align__(16) char smem[22544];
    int blk = blockIdx.x, tid = threadIdx.x;

    int role, id;
    if (blk < 1152) {
        int g = blk / 3, r3 = blk - g * 3;
        role = r3 == 0 ? 0 : 1;
        id = r3 == 0 ? g : g * 2 + (r3 - 1);
    } else if (blk < 1408) { role = 1; id = 768 + (blk - 1152); }
    else { role = 2; id = blk - 1408; }

    if (role == 1) {
        // ---------------- char bi-LSTM (readlane + named weights) ----------------
        float (*xg)[NG] = (float (*)[NG])smem;            // 12800
        float (*gsb)[NG] = (float (*)[NG])(smem + 12800); // 1600
        int*   scid = (int*)(smem + 14400);               // 64

        int n = id >> 1, dir = id & 1;
        const float* Whh = dir ? Whh_b : Whh_f;
        int lane = tid & 63;

        int len = char_count[n];
        if (len < 1) len = 1;
        if (tid < Tc) {
            int st = dir ? (tid < len ? len - 1 - tid : tid) : tid;  // bwd: reverse valid prefix
            scid[tid] = char_ids[n * Tc + st];
        }
        __syncthreads();

        // stage xproj rows as float4 (row stride 200 floats = 800B, 16B aligned)
        for (int e = tid; e < Tc * (NG / 4); e += 256) {
            int t = e / 50, q = e - t * 50;
            ((float4*)xg[t])[q] = ((const float4*)&xpt[(dir * CV + scid[t]) * NG])[q];
        }
        // recurrent weight row -> 25 NAMED float2 locals (allocator-resident)
        int wrow = tid < NG ? tid : NG - 1;
        bool istanh = (tid >= 100 && tid < 150);          // cell-gate rows
        const float2* wp = (const float2*)&Whh[wrow * 50];   // 8B aligned
        #define LW(i) float2 w##i = wp[i];
        LW(0) LW(1) LW(2) LW(3) LW(4) LW(5) LW(6) LW(7) LW(8) LW(9)
        LW(10) LW(11) LW(12) LW(13) LW(14) LW(15) LW(16) LW(17) LW(18) LW(19)
        LW(20) LW(21) LW(22) LW(23) LW(24)
        #undef LW
        __syncthreads();

        int ch = lane < 50 ? lane : 49;                   // state channel this lane tracks
        float c = 0.f, h = 0.f, maxv = -FLT_MAX;
        #pragma unroll
        for (int t = 0; t < Tc; t++) {
            // ---- A: gate pre-activation, h broadcast via readlane ----
            int hb = __float_as_int(h);
            float g0 = xg[t][wrow], g1 = 0.f;
            #define FMA2(i) \
                g0 = fmaf(__int_as_float(__builtin_amdgcn_readlane(hb, 2*i)),     w##i.x, g0); \
                g1 = fmaf(__int_as_float(__builtin_amdgcn_readlane(hb, 2*i + 1)), w##i.y, g1);
            FMA2(0) FMA2(1) FMA2(2) FMA2(3) FMA2(4) FMA2(5) FMA2(6) FMA2(7)
            FMA2(8) FMA2(9) FMA2(10) FMA2(11) FMA2(12) FMA2(13) FMA2(14) FMA2(15)
            FMA2(16) FMA2(17) FMA2(18) FMA2(19) FMA2(20) FMA2(21) FMA2(22) FMA2(23)
            FMA2(24)
            #undef FMA2
            float g = g0 + g1;
            if (tid < NG)
                gsb[t & 1][tid] = istanh ? tanh_fast(g) : sigmoid_fast(g);
            __syncthreads();                               // only barrier per step
            // ---- B: state update, redundant in every wave (h stays lane-local).
            // Race-free: A(t+2)'s write to gsb[t&1] is after barrier(t+1),
            // which every wave reaches only after its B(t) reads.
            float si = gsb[t & 1][ch];
            float sf = gsb[t & 1][ch + 50];
            float tg = gsb[t & 1][ch + 100];
            float so = gsb[t & 1][ch + 150];
            c = sf * c + si * tg;
            h = so * tanh_fast(c);
            if (t < len) maxv = fmaxf(maxv, h);            // ragged max
        }
        if (tid < 50)
            out[(size_t)n * OUTC + (Hh + WD) + dir * Dc + tid] = maxv;
    } else if (role == 0) {
        // ------- word_reps masked max, branchless, 4 rows x float4-h -------
        float (*sm)[4] = (float (*)[4])smem;                        // 6144
        float (*sacc)[4][256] = (float (*)[4][256])(smem + 6144);   // 16384
        float* sminv = (float*)(smem + 22528);

        int hc  = id % 3;              // h-chunk of 256
        int lt  = (id / 3) & 63;       // l-tile of 4
        int b   = id / 192;
        int l0  = lt * 4;

        // stage mask bias, coalesced global reads (s-fast within a row)
        const int* pm = p2w + ((size_t)(b * Ll + l0)) * Ss;
        for (int e = tid; e < 4 * Ss; e += 256) {
            int r = e / Ss, s = e - r * Ss;
            sm[s][r] = pm[r * Ss + s] ? 0.f : -FLT_MAX;
        }
        if (tid < 64) {
            float m = fminf(minp[tid], minp[tid + 64]);
            #pragma unroll
            for (int off = 32; off; off >>= 1) m = fminf(m, __shfl_down(m, off, 64));
            if (tid == 0) *sminv = m;
        }
        __syncthreads();

        int w    = tid >> 6;           // wave -> s range [w*96, w*96+96)
        int lane = tid & 63;
        int s0 = w * 96;

        // bert row s = 192 float4; lane covers h = hc*256 + lane*4 .. +3
        const float4* bb4 = (const float4*)(bert + (size_t)b * Ss * Hh) + hc * 64 + lane;
        float4 acc[4];
        #pragma unroll
        for (int r = 0; r < 4; r++) acc[r] = make_float4(-FLT_MAX, -FLT_MAX, -FLT_MAX, -FLT_MAX);

        for (int jo = 0; jo < 96; jo += 8) {       // 8 loads in flight per group
            float4 v[8];
            #pragma unroll
            for (int k = 0; k < 8; k++) v[k] = bb4[(size_t)(s0 + jo + k) * 192];
            #pragma unroll
            for (int k = 0; k < 8; k++) {
                int j = s0 + jo + k;
                float4 q = *(const float4*)&sm[j][0];   // ONE b128 broadcast: rows 0..3
                acc[0].x = fmaxf(acc[0].x, v[k].x + q.x);
                acc[0].y = fmaxf(acc[0].y, v[k].y + q.x);
                acc[0].z = fmaxf(acc[0].z, v[k].z + q.x);
                acc[0].w = fmaxf(acc[0].w, v[k].w + q.x);
                acc[1].x = fmaxf(acc[1].x, v[k].x + q.y);
                acc[1].y = fmaxf(acc[1].y, v[k].y + q.y);
                acc[1].z = fmaxf(acc[1].z, v[k].z + q.y);
                acc[1].w = fmaxf(acc[1].w, v[k].w + q.y);
                acc[2].x = fmaxf(acc[2].x, v[k].x + q.z);
                acc[2].y = fmaxf(acc[2].y, v[k].y + q.z);
                acc[2].z = fmaxf(acc[2].z, v[k].z + q.z);
                acc[2].w = fmaxf(acc[2].w, v[k].w + q.z);
                acc[3].x = fmaxf(acc[3].x, v[k].x + q.w);
                acc[3].y = fmaxf(acc[3].y, v[k].y + q.w);
                acc[3].z = fmaxf(acc[3].z, v[k].z + q.w);
                acc[3].w = fmaxf(acc[3].w, v[k].w + q.w);
            }
        }
        #pragma unroll
        for (int r = 0; r < 4; r++)
            *(float4*)&sacc[w][r][lane * 4] = acc[r];
        __syncthreads();

        float mv = *sminv;
        for (int e = tid; e < 4 * 256; e += 256) {
            int r = e >> 8, cx = e & 255;
            float m = fmaxf(fmaxf(sacc[0][r][cx], sacc[1][r][cx]),
                            fmaxf(sacc[2][r][cx], sacc[3][r][cx]));
            if (m == -FLT_MAX) m = mv;             // fully-masked row -> global min fill
            out[((size_t)(b * Ll + l0 + r)) * OUTC + hc * 256 + cx] = m;
        }
    } else {
        // ---------------- word embedding gather ----------------
        for (int i = id * 256 + tid; i < Bb * Ll * WD; i += 64 * 256) {
            int bl = i / WD, d = i - bl * WD;
            out[(size_t)bl * OUTC + Hh + d] = word_table[(size_t)word_ids[bl] * WD + d];
        }
    }
}

extern "C" void kernel_launch(void* const* d_in, const int* in_sizes, int n_in,
                              void* d_out, int out_size, void* d_ws, size_t ws_size,
                              hipStream_t stream) {
    const float* bert       = (const float*)d_in[0];
    const int*   p2w        = (const int*)d_in[1];
    const int*   word_ids   = (const int*)d_in[2];
    const int*   char_count = (const int*)d_in[3];
    const int*   char_ids   = (const int*)d_in[4];
    // d_in[5] token_masks_char: consistent with char_count, unused
    const float* word_table = (const float*)d_in[6];
    const float* char_table = (const float*)d_in[7];
    const float* Wih_f = (const float*)d_in[8];
    const float* Whh_f = (const float*)d_in[9];
    const float* bih_f = (const float*)d_in[10];
    const float* bhh_f = (const float*)d_in[11];
    const float* Wih_b = (const float*)d_in[12];
    const float* Whh_b = (const float*)d_in[13];
    const float* bih_b = (const float*)d_in[14];
    const float* bhh_b = (const float*)d_in[15];
    float* out = (float*)d_out;

    float* minp = (float*)d_ws;          // 128 floats
    float* xpt  = minp + 128;            // 2*128*200 floats

    kernel1<<<144, 256, 0, stream>>>(
        bert, char_table, Wih_f, bih_f, bhh_f, Wih_b, bih_b, bhh_b,
        minp, xpt);
    kernel2<<<1472, 256, 0, stream>>>(
        char_ids, char_count, Whh_f, Whh_b, xpt, bert, p2w, minp,
        word_ids, word_table, out);
}

// Round 13
// 123.169 us; speedup vs baseline: 1.0163x; 1.0036x over previous
//
#include <hip/hip_runtime.h>
#include <float.h>

#define Bb 2
#define Ll 256
#define Ss 384
#define Hh 768
#define Tc 16
#define Dc 50
#define WD 100
#define CV 128
#define NG 200     // 4*Dc gates
#define OUTC 968   // H + WD + 2*Dc

// ws layout (floats):
//   [0, 128)      minv partials
//   [128, ...)    xproj table [2][128][200], bias folded in

__device__ inline float tanh_fast(float x) {
    float e = __expf(2.f * x);
    return 1.f - 2.f / (e + 1.f);
}
__device__ inline float sigmoid_fast(float x) {
    return 1.f / (1.f + __expf(-x));
}

// ================= kernel 1: min partials | xproj =================
// grid 144: [0,128) min, [128,144) xproj

__global__ __launch_bounds__(256) void kernel1(
        const float* __restrict__ bert, const float* __restrict__ char_table,
        const float* __restrict__ Wih_f, const float* __restrict__ bih_f, const float* __restrict__ bhh_f,
        const float* __restrict__ Wih_b, const float* __restrict__ bih_b, const float* __restrict__ bhh_b,
        float* __restrict__ minp, float* __restrict__ xpt) {
    int blk = blockIdx.x, tid = threadIdx.x;
    if (blk < 128) {
        const int n4 = (Bb * Ss * Hh) / 4;       // 147456 float4
        const float4* b4 = (const float4*)bert;
        float m = FLT_MAX;
        for (int i = blk * 256 + tid; i < n4; i += 128 * 256) {
            float4 v = b4[i];
            m = fminf(m, fminf(fminf(v.x, v.y), fminf(v.z, v.w)));
        }
        #pragma unroll
        for (int off = 32; off; off >>= 1) m = fminf(m, __shfl_down(m, off, 64));
        __shared__ float red[4];
        if ((tid & 63) == 0) red[tid >> 6] = m;
        __syncthreads();
        if (tid == 0) minp[blk] = fminf(fminf(red[0], red[1]), fminf(red[2], red[3]));
    } else {
        int idx = blk - 128;            // dir*8 + cid-chunk
        int dir = idx >> 3, c0 = (idx & 7) * 16;
        const float* Wih = dir ? Wih_b : Wih_f;
        const float* bih = dir ? bih_b : bih_f;
        const float* bhh = dir ? bhh_b : bhh_f;
        __shared__ float ct[16][Dc];
        for (int e = tid; e < 16 * Dc; e += 256)
            ((float*)ct)[e] = char_table[c0 * Dc + e];
        __syncthreads();
        if (tid < NG) {
            float w[Dc];
            #pragma unroll
            for (int j = 0; j < Dc; j++) w[j] = Wih[tid * Dc + j];
            float bias = bih[tid] + bhh[tid];
            for (int cid = 0; cid < 16; cid++) {
                float a = bias;
                #pragma unroll
                for (int j = 0; j < Dc; j++) a += w[j] * ct[cid][j];
                xpt[(dir * CV + c0 + cid) * NG + tid] = a;
            }
        }
    }
}

// ================= kernel2: fused lstm | word+embed =================
// grid 1408 with __launch_bounds__(256,6): ALL blocks co-resident in ONE
// occupancy round (capacity 6 blk/CU x 256 CU = 1536 >= 1408).
//   R9-R12 launched 1472 blocks at 4/CU (capacity 1024) => TWO occupancy
//   rounds; makespan = round1(~20us, = per-block wall of the latency-bound
//   lstm) + straggler round2(~16us) = the ~36us invariant that no per-block
//   optimization could move. Single round => makespan ~ max block wall.
// Mapping: blk<1152: blk%3==0 -> word id blk/3, else lstm id 2*(blk/3)+blk%3-1;
//          blk>=1152: lstm id 768+(blk-1152). Embed folded into word role.
// VGPR cap at 6 waves/EU is ~85: word in-flight load group cut 8->4 float4
// (peak live ~45 regs); lstm named-float2 weight set ~50+misc fits.
// LDS 22.5KB x 6 = 135KB <= 160KB.

__global__ __launch_bounds__(256, 6) void kernel2(
        const int* __restrict__ char_ids, const int* __restrict__ char_count,
        const float* __restrict__ Whh_f, const float* __restrict__ Whh_b,
        const float* __restrict__ xpt,
        const float* __restrict__ bert, const int* __restrict__ p2w,
        const float* __restrict__ minp,
        const int* __restrict__ word_ids, const float* __restrict__ word_table,
        float* __restrict__ out) {
    __shared__ __align__(16) char smem[22544];
    int blk = blockIdx.x, tid = threadIdx.x;

    int role, id;
    if (blk < 1152) {
        int g = blk / 3, r3 = blk - g * 3;
        role = r3 == 0 ? 0 : 1;
        id = r3 == 0 ? g : g * 2 + (r3 - 1);
    } else { role = 1; id = 768 + (blk - 1152); }

    if (role == 1) {
        // ---------------- char bi-LSTM (readlane + named weights) ----------------
        float (*xg)[NG] = (float (*)[NG])smem;            // 12800
        float (*gsb)[NG] = (float (*)[NG])(smem + 12800); // 1600
        int*   scid = (int*)(smem + 14400);               // 64

        int n = id >> 1, dir = id & 1;
        const float* Whh = dir ? Whh_b : Whh_f;
        int lane = tid & 63;

        int len = char_count[n];
        if (len < 1) len = 1;
        if (tid < Tc) {
            int st = dir ? (tid < len ? len - 1 - tid : tid) : tid;  // bwd: reverse valid prefix
            scid[tid] = char_ids[n * Tc + st];
        }
        __syncthreads();

        // stage xproj rows as float4 (row stride 200 floats = 800B, 16B aligned)
        for (int e = tid; e < Tc * (NG / 4); e += 256) {
            int t = e / 50, q = e - t * 50;
            ((float4*)xg[t])[q] = ((const float4*)&xpt[(dir * CV + scid[t]) * NG])[q];
        }
        // recurrent weight row -> 25 NAMED float2 locals (allocator-resident)
        int wrow = tid < NG ? tid : NG - 1;
        bool istanh = (tid >= 100 && tid < 150);          // cell-gate rows
        const float2* wp = (const float2*)&Whh[wrow * 50];   // 8B aligned
        #define LW(i) float2 w##i = wp[i];
        LW(0) LW(1) LW(2) LW(3) LW(4) LW(5) LW(6) LW(7) LW(8) LW(9)
        LW(10) LW(11) LW(12) LW(13) LW(14) LW(15) LW(16) LW(17) LW(18) LW(19)
        LW(20) LW(21) LW(22) LW(23) LW(24)
        #undef LW
        __syncthreads();

        int ch = lane < 50 ? lane : 49;                   // state channel this lane tracks
        float c = 0.f, h = 0.f, maxv = -FLT_MAX;
        #pragma unroll
        for (int t = 0; t < Tc; t++) {
            // ---- A: gate pre-activation, h broadcast via readlane ----
            int hb = __float_as_int(h);
            float g0 = xg[t][wrow], g1 = 0.f;
            #define FMA2(i) \
                g0 = fmaf(__int_as_float(__builtin_amdgcn_readlane(hb, 2*i)),     w##i.x, g0); \
                g1 = fmaf(__int_as_float(__builtin_amdgcn_readlane(hb, 2*i + 1)), w##i.y, g1);
            FMA2(0) FMA2(1) FMA2(2) FMA2(3) FMA2(4) FMA2(5) FMA2(6) FMA2(7)
            FMA2(8) FMA2(9) FMA2(10) FMA2(11) FMA2(12) FMA2(13) FMA2(14) FMA2(15)
            FMA2(16) FMA2(17) FMA2(18) FMA2(19) FMA2(20) FMA2(21) FMA2(22) FMA2(23)
            FMA2(24)
            #undef FMA2
            float g = g0 + g1;
            if (tid < NG)
                gsb[t & 1][tid] = istanh ? tanh_fast(g) : sigmoid_fast(g);
            __syncthreads();                               // only barrier per step
            // ---- B: state update, redundant in every wave (h stays lane-local).
            // Race-free: A(t+2)'s write to gsb[t&1] is after barrier(t+1),
            // which every wave reaches only after its B(t) reads.
            float si = gsb[t & 1][ch];
            float sf = gsb[t & 1][ch + 50];
            float tg = gsb[t & 1][ch + 100];
            float so = gsb[t & 1][ch + 150];
            c = sf * c + si * tg;
            h = so * tanh_fast(c);
            if (t < len) maxv = fmaxf(maxv, h);            // ragged max
        }
        if (tid < 50)
            out[(size_t)n * OUTC + (Hh + WD) + dir * Dc + tid] = maxv;
    } else {
        // ------- word_reps masked max, branchless, 4 rows x float4-h -------
        float (*sm)[4] = (float (*)[4])smem;                        // 6144
        float (*sacc)[4][256] = (float (*)[4][256])(smem + 6144);   // 16384
        float* sminv = (float*)(smem + 22528);

        int hc  = id % 3;              // h-chunk of 256
        int lt  = (id / 3) & 63;       // l-tile of 4
        int b   = id / 192;
        int l0  = lt * 4;

        // stage mask bias, coalesced global reads (s-fast within a row)
        const int* pm = p2w + ((size_t)(b * Ll + l0)) * Ss;
        for (int e = tid; e < 4 * Ss; e += 256) {
            int r = e / Ss, s = e - r * Ss;
            sm[s][r] = pm[r * Ss + s] ? 0.f : -FLT_MAX;
        }
        if (tid < 64) {
            float m = fminf(minp[tid], minp[tid + 64]);
            #pragma unroll
            for (int off = 32; off; off >>= 1) m = fminf(m, __shfl_down(m, off, 64));
            if (tid == 0) *sminv = m;
        }
        __syncthreads();

        int w    = tid >> 6;           // wave -> s range [w*96, w*96+96)
        int lane = tid & 63;
        int s0 = w * 96;

        // bert row s = 192 float4; lane covers h = hc*256 + lane*4 .. +3
        const float4* bb4 = (const float4*)(bert + (size_t)b * Ss * Hh) + hc * 64 + lane;
        float4 acc[4];
        #pragma unroll
        for (int r = 0; r < 4; r++) acc[r] = make_float4(-FLT_MAX, -FLT_MAX, -FLT_MAX, -FLT_MAX);

        for (int jo = 0; jo < 96; jo += 4) {       // 4 loads in flight (VGPR cap 85)
            float4 v[4];
            #pragma unroll
            for (int k = 0; k < 4; k++) v[k] = bb4[(size_t)(s0 + jo + k) * 192];
            #pragma unroll
            for (int k = 0; k < 4; k++) {
                int j = s0 + jo + k;
                float4 q = *(const float4*)&sm[j][0];   // ONE b128 broadcast: rows 0..3
                acc[0].x = fmaxf(acc[0].x, v[k].x + q.x);
                acc[0].y = fmaxf(acc[0].y, v[k].y + q.x);
                acc[0].z = fmaxf(acc[0].z, v[k].z + q.x);
                acc[0].w = fmaxf(acc[0].w, v[k].w + q.x);
                acc[1].x = fmaxf(acc[1].x, v[k].x + q.y);
                acc[1].y = fmaxf(acc[1].y, v[k].y + q.y);
                acc[1].z = fmaxf(acc[1].z, v[k].z + q.y);
                acc[1].w = fmaxf(acc[1].w, v[k].w + q.y);
                acc[2].x = fmaxf(acc[2].x, v[k].x + q.z);
                acc[2].y = fmaxf(acc[2].y, v[k].y + q.z);
                acc[2].z = fmaxf(acc[2].z, v[k].z + q.z);
                acc[2].w = fmaxf(acc[2].w, v[k].w + q.z);
                acc[3].x = fmaxf(acc[3].x, v[k].x + q.w);
                acc[3].y = fmaxf(acc[3].y, v[k].y + q.w);
                acc[3].z = fmaxf(acc[3].z, v[k].z + q.w);
                acc[3].w = fmaxf(acc[3].w, v[k].w + q.w);
            }
        }
        #pragma unroll
        for (int r = 0; r < 4; r++)
            *(float4*)&sacc[w][r][lane * 4] = acc[r];
        __syncthreads();

        float mv = *sminv;
        for (int e = tid; e < 4 * 256; e += 256) {
            int r = e >> 8, cx = e & 255;
            float m = fmaxf(fmaxf(sacc[0][r][cx], sacc[1][r][cx]),
                            fmaxf(sacc[2][r][cx], sacc[3][r][cx]));
            if (m == -FLT_MAX) m = mv;             // fully-masked row -> global min fill
            out[((size_t)(b * Ll + l0 + r)) * OUTC + hc * 256 + cx] = m;
        }

        // ---------------- word embedding gather (folded; one slice/block) ----------------
        for (int i = id * 256 + tid; i < Bb * Ll * WD; i += 384 * 256) {
            int bl = i / WD, d = i - bl * WD;
            out[(size_t)bl * OUTC + Hh + d] = word_table[(size_t)word_ids[bl] * WD + d];
        }
    }
}

extern "C" void kernel_launch(void* const* d_in, const int* in_sizes, int n_in,
                              void* d_out, int out_size, void* d_ws, size_t ws_size,
                              hipStream_t stream) {
    const float* bert       = (const float*)d_in[0];
    const int*   p2w        = (const int*)d_in[1];
    const int*   word_ids   = (const int*)d_in[2];
    const int*   char_count = (const int*)d_in[3];
    const int*   char_ids   = (const int*)d_in[4];
    // d_in[5] token_masks_char: consistent with char_count, unused
    const float* word_table = (const float*)d_in[6];
    const float* char_table = (const float*)d_in[7];
    const float* Wih_f = (const float*)d_in[8];
    const float* Whh_f = (const float*)d_in[9];
    const float* bih_f = (const float*)d_in[10];
    const float* bhh_f = (const float*)d_in[11];
    const float* Wih_b = (const float*)d_in[12];
    const float* Whh_b = (const float*)d_in[13];
    const float* bih_b = (const float*)d_in[14];
    const float* bhh_b = (const float*)d_in[15];
    float* out = (float*)d_out;

    float* minp = (float*)d_ws;          // 128 floats
    float* xpt  = minp + 128;            // 2*128*200 floats

    kernel1<<<144, 256, 0, stream>>>(
        bert, char_table, Wih_f, bih_f, bhh_f, Wih_b, bih_b, bhh_b,
        minp, xpt);
    kernel2<<<1408, 256, 0, stream>>>(
        char_ids, char_count, Whh_f, Whh_b, xpt, bert, p2w, minp,
        word_ids, word_table, out);
}